// Round 1
// 70.478 us; speedup vs baseline: 1.0049x; 1.0049x over previous
//
#include <hip/hip_runtime.h>

// DownscaleLabel: label [8,1024,1024] int32 in [-1,6] -> out [8,1,64,64] int32.
// Per 16x16 block: histogram of (label & 7) (-1 -> bin 7), first-max argmax,
// -1 if argmax==7 or max count < 192 (0.75*256). All-integer, exact.
//
// v2 layout: 2048 blocks = one per (b, th, col-quadrant). Each block covers
// 16 rows x 256 cols (16 tw tiles). 256 threads = 4 waves; wave w reads rows
// {w, w+4, w+8, w+12}, each row as 64 lanes x int4 = contiguous 1 KiB
// (perfectly coalesced), 4 independent loads/thread.
//   -> 8 blocks/CU = 32 waves/CU (max occupancy) vs v1's 8 waves/CU.
// Histogram: single u64 with 8 classes x 8-bit (per-thread max 16/bin,
// post-4-lane-reduce max 64/bin -> fits). ~5 VALU ops/element vs v1's ~9.
// Expand to 16-bit fields only at the cross-wave LDS combine (max 256/bin).

#define B_ 8
#define H_ 1024
#define W_ 1024
#define TH_ 64
#define TW_ 64

__global__ __launch_bounds__(256, 8) void downscale_label_kernel(
    const int* __restrict__ label, int* __restrict__ out) {
  const int t = threadIdx.x;
  const int w = t >> 6;        // wave 0..3
  const int l = t & 63;        // lane
  const int bid = blockIdx.x;  // (b*64 + th)*4 + q
  const int q = bid & 3;       // column quadrant (256 cols)
  const int bth = bid >> 2;    // b*64 + th  (H == 64*16 so strip base folds)

  // strip base: (b*H + th*16)*W == bth*16*W
  const int4* p = reinterpret_cast<const int4*>(
      label + (size_t)bth * 16 * W_ + (size_t)q * 256 + (size_t)l * 4);

  // Load all 4 rows up-front (static indexing -> registers, 4-deep MLP).
  int4 v[4];
#pragma unroll
  for (int r = 0; r < 4; ++r) v[r] = p[(w + r * 4) * (W_ / 4)];

  unsigned long long h = 0ull;  // 8 classes x 8-bit counts
#pragma unroll
  for (int r = 0; r < 4; ++r) {
    const int vals[4] = {v[r].x, v[r].y, v[r].z, v[r].w};
#pragma unroll
    for (int j = 0; j < 4; ++j) {
      const int cls = vals[j] & 7;      // -1 -> 7, 0..6 unchanged
      h += 1ull << (cls << 3);          // bump byte field cls
    }
  }

  // Reduce across the 4 lanes sharing one tw (lanes 4k..4k+3, same wave).
  h += __shfl_xor(h, 1, 64);
  h += __shfl_xor(h, 2, 64);           // now max 64 per byte field

  // Cross-wave combine: 16 tw tiles per block, 4 waves.
  __shared__ unsigned long long smem[4][16];
  if ((l & 3) == 0) smem[w][l >> 2] = h;
  __syncthreads();

  if (t < 16) {
    const unsigned long long M = 0x00FF00FF00FF00FFull;
    unsigned long long e0 = 0ull, e1 = 0ull;  // 16-bit fields
#pragma unroll
    for (int ww = 0; ww < 4; ++ww) {
      const unsigned long long x = smem[ww][t];
      e0 += x & M;          // classes 0,2,4,6 at fields 0..3
      e1 += (x >> 8) & M;   // classes 1,3,5,7 at fields 0..3
    }
    int best = 0;
    int bc = (int)(e0 & 0xFFFF);        // class 0 count
#pragma unroll
    for (int c = 1; c < 8; ++c) {
      const unsigned long long src = (c & 1) ? e1 : e0;
      const int cnt = (int)((src >> ((c >> 1) << 4)) & 0xFFFF);
      if (cnt > bc) { bc = cnt; best = c; }  // strict > keeps first max
    }
    out[bth * TW_ + q * 16 + t] = (best == 7 || bc < 192) ? -1 : best;
  }
}

extern "C" void kernel_launch(void* const* d_in, const int* in_sizes, int n_in,
                              void* d_out, int out_size, void* d_ws, size_t ws_size,
                              hipStream_t stream) {
  const int* label = (const int*)d_in[0];
  int* out = (int*)d_out;
  downscale_label_kernel<<<B_ * TH_ * 4, 256, 0, stream>>>(label, out);
}